// Round 4
// baseline (5159.555 us; speedup 1.0000x reference)
//
#include <hip/hip_runtime.h>
#include <hip/hip_bf16.h>

#define B_   32
#define N_   512
#define D_   768
#define H_   12
#define HID_ 3072
#define L_   12
#define M_   (B_*N_)   // 16384

typedef __attribute__((ext_vector_type(8))) short short8_t;
typedef __attribute__((ext_vector_type(4))) short short4_t;
typedef __attribute__((ext_vector_type(4))) float f32x4;
typedef __hip_bfloat16 bf16;

__device__ __forceinline__ void gll16(const void* g, void* l){
    __builtin_amdgcn_global_load_lds((const __attribute__((address_space(1))) void*)g,
                                     (__attribute__((address_space(3))) void*)l, 16, 0, 0);
}

// ---------------- embedding: h = x@W_xemb + b + pos ----------------
__global__ __launch_bounds__(256) void embed_kernel(
    const float* __restrict__ x, const float* __restrict__ Wx,
    const float* __restrict__ bx, float* __restrict__ h)
{
    long idx = (long)blockIdx.x * 256 + threadIdx.x;   // < 16384*768
    int d = (int)(idx % 768);
    long m = idx / 768;
    int n = (int)(m % 512);
    float acc = bx[d];
    const float* xr = x + m * 16;
    #pragma unroll
    for (int k = 0; k < 16; ++k) acc = fmaf(xr[k], Wx[k*768 + d], acc);
    int K = (d < 384) ? d : d - 384;
    float ang = (float)n * 3.14159265358979323846f * expf(-(2.0f*(float)K/768.0f) * 7.624618986159398f);
    acc += (d < 384) ? sinf(ang) : cosf(ang);
    h[idx] = acc;
}

// ---------------- c_silu = silu(ds_table[dataset] + sg_table[spacegroup]) ----------------
__global__ __launch_bounds__(256) void csilu_kernel(
    const float* __restrict__ ds_t, const float* __restrict__ sg_t,
    const int* __restrict__ dataset, const int* __restrict__ sg, float* __restrict__ out)
{
    int idx = blockIdx.x*256 + threadIdx.x;   // 32*768
    int b = idx / 768, d = idx % 768;
    float c = ds_t[dataset[b]*768 + d] + sg_t[sg[b]*768 + d];
    out[idx] = c / (1.0f + expf(-c));
}

// ---------------- mods partials v2: 16-b groups, csilu in LDS ----------------
__global__ __launch_bounds__(256) void mods_part_kernel(
    const float* __restrict__ csilu, const float* __restrict__ W,
    float* __restrict__ part, int Nd2, long wLayerStride)
{
    __shared__ float cs[16][96];
    int n2 = blockIdx.x*256 + threadIdx.x;
    int l = blockIdx.y, z = blockIdx.z;
    int kz = z >> 1, bg = z & 1;
    int L = gridDim.y;
    for (int t = threadIdx.x; t < 16*96; t += 256){
        int bb = t / 96, kk = t - bb*96;
        cs[bb][kk] = csilu[(bg*16 + bb)*768 + kz*96 + kk];
    }
    __syncthreads();
    const float2* Wl = (const float2*)(W + (long)l*wLayerStride);
    float2 acc[16];
    #pragma unroll
    for (int b=0;b<16;b++) acc[b] = make_float2(0.f, 0.f);
    for (int k=0;k<96;++k){
        float2 wv = Wl[(long)(kz*96 + k)*Nd2 + n2];
        #pragma unroll
        for (int b=0;b<16;b++){
            float c = cs[b][k];
            acc[b].x = fmaf(c, wv.x, acc[b].x);
            acc[b].y = fmaf(c, wv.y, acc[b].y);
        }
    }
    float2* pp = (float2*)part + ((long)(kz*L + l)*32 + bg*16)*Nd2 + n2;
    #pragma unroll
    for (int b=0;b<16;b++) pp[(long)b*Nd2] = acc[b];
}

__global__ __launch_bounds__(256) void mods_reduce_kernel(
    const float* __restrict__ part, const float* __restrict__ bias,
    float* __restrict__ out, int Nd, int L)
{
    long idx = (long)blockIdx.x*256 + threadIdx.x;  // over L*32*Nd
    int n = (int)(idx % Nd);
    long r = idx / Nd;
    int b = (int)(r & 31);
    int l = (int)(r >> 5);
    float s = bias[(long)l*Nd + n];
    #pragma unroll
    for (int z=0;z<8;z++) s += part[((long)(z*L + l)*32 + b)*Nd + n];
    out[idx] = s;
}

// ---------------- fused per-layer weight transpose fp32 [K][N] -> bf16 [N][K] ----------------
__global__ __launch_bounds__(256) void transpose4_kernel(
    const float* __restrict__ Wqkv, const float* __restrict__ Wo,
    const float* __restrict__ W1,  const float* __restrict__ W2,
    bf16* __restrict__ wqT, bf16* __restrict__ woT,
    bf16* __restrict__ w1T, bf16* __restrict__ w2T)
{
    __shared__ float t[32][33];
    int tt = blockIdx.x;
    const float* src; bf16* dst; int K, Nd, nx;
    if (tt < 1728){ src=Wqkv; dst=wqT; K=768; Nd=2304; nx=72; }
    else if (tt < 2304){ src=Wo; dst=woT; K=768; Nd=768; nx=24; tt -= 1728; }
    else if (tt < 4608){ src=W1; dst=w1T; K=768; Nd=3072; nx=96; tt -= 2304; }
    else { src=W2; dst=w2T; K=3072; Nd=768; nx=24; tt -= 4608; }
    int n0 = (tt % nx)*32, k0 = (tt / nx)*32;
    int tx = threadIdx.x & 31, ty = threadIdx.x >> 5;   // 32 x 8
    #pragma unroll
    for (int j=0;j<4;j++)
        t[ty + j*8][tx] = src[(long)(k0 + ty + j*8)*Nd + n0 + tx];
    __syncthreads();
    #pragma unroll
    for (int j=0;j<4;j++)
        dst[(long)(n0 + ty + j*8)*K + k0 + tx] = __float2bfloat16(t[tx][ty + j*8]);
}

// ---------------- LayerNorm + modulate -> bf16 (wave-per-row, float4) ----------------
__global__ __launch_bounds__(256) void ln_mod_kernel(
    const float* __restrict__ h, const float* __restrict__ shiftB,
    const float* __restrict__ scaleB, int modsStride, bf16* __restrict__ out)
{
    int wave = threadIdx.x >> 6, lane = threadIdx.x & 63;
    long row = (long)blockIdx.x*4 + wave;
    int b = (int)(row >> 9);
    const float4* xr = (const float4*)(h + row*768);
    float4 v[3];
    float s = 0.f, ss = 0.f;
    #pragma unroll
    for (int i=0;i<3;i++){
        v[i] = xr[lane + i*64];
        s  += v[i].x + v[i].y + v[i].z + v[i].w;
        ss += v[i].x*v[i].x + v[i].y*v[i].y + v[i].z*v[i].z + v[i].w*v[i].w;
    }
    #pragma unroll
    for (int o=1;o<64;o<<=1){ s += __shfl_xor(s,o,64); ss += __shfl_xor(ss,o,64); }
    float mean = s * (1.0f/768.0f);
    float var  = ss * (1.0f/768.0f) - mean*mean;
    float rstd = rsqrtf(var + 1e-6f);
    const float4* sh4 = (const float4*)(shiftB + (long)b*modsStride);
    const float4* sc4 = (const float4*)(scaleB + (long)b*modsStride);
    short4_t* orow = (short4_t*)(out + row*768);
    #pragma unroll
    for (int i=0;i<3;i++){
        float4 sh = sh4[lane + i*64];
        float4 sc = sc4[lane + i*64];
        float o0 = (v[i].x-mean)*rstd*(1.f+sc.x) + sh.x;
        float o1 = (v[i].y-mean)*rstd*(1.f+sc.y) + sh.y;
        float o2 = (v[i].z-mean)*rstd*(1.f+sc.z) + sh.z;
        float o3 = (v[i].w-mean)*rstd*(1.f+sc.w) + sh.w;
        bf16 b0 = __float2bfloat16(o0), b1 = __float2bfloat16(o1);
        bf16 b2 = __float2bfloat16(o2), b3 = __float2bfloat16(o3);
        short4_t pk;
        pk[0] = *(short*)&b0; pk[1] = *(short*)&b1;
        pk[2] = *(short*)&b2; pk[3] = *(short*)&b3;
        orow[lane + i*64] = pk;
    }
}

// gelu(tanh approx) via sigmoid identity: 0.5x(1+tanh(z)) = x * sigmoid(2z)
__device__ __forceinline__ float gelu_f(float x){
    float z2 = 1.5957691216057308f * x * (1.0f + 0.044715f*x*x);
    return x / (1.0f + __expf(-z2));
}

// ---------------- 128x192 pipelined bf16 MFMA GEMM (round-3 variant) ----------------
template<int MODE>
__global__ __launch_bounds__(256, 2) void gemm128_kernel(
    const bf16* __restrict__ A, const bf16* __restrict__ Bw,
    const float* __restrict__ bias, bf16* __restrict__ outBf,
    float* __restrict__ hres, const float* __restrict__ gate,
    int Nd, int Kd, int gateStride)
{
    __shared__ __align__(16) short lds[40960];   // 80 KiB
    int tid = threadIdx.x;
    int lane = tid & 63, wave = tid >> 6;
    int frow = lane & 15, g = lane >> 4;

    int nx = gridDim.x;
    int bid = blockIdx.y * nx + blockIdx.x;
    int xcd = bid & 7;
    int wq  = bid >> 3;
    int mt  = xcd * 16 + (wq & 15);
    int ct  = wq >> 4;
    int m0 = mt * 128, n0 = ct * 192;
    int wn = wave * 48;

    const short* Ag = (const short*)A;
    const short* Bg = (const short*)Bw;
    int r0 = tid >> 3, s0 = (tid & 7) ^ ((tid >> 3) & 7);
    const short* aSrc = Ag + (long)(m0 + r0)*Kd + s0*8;
    const short* bSrc = Bg + (long)(n0 + r0)*Kd + s0*8;
    long rj = (long)32*Kd;
    int wbase = wave*512;

    int aFrag = frow*64;
    int bFrag = (wn + frow)*64;
    int slotK0 = (g ^ (frow & 7))*8;
    int slotK1 = ((4+g) ^ (frow & 7))*8;

    f32x4 acc[8][3];
    #pragma unroll
    for (int i=0;i<8;i++)
        #pragma unroll
        for (int j=0;j<3;j++) acc[i][j] = (f32x4){0.f,0.f,0.f,0.f};

    int NT = Kd >> 6;

#define STAGE(kt, ps) { \
    int par_ = (kt)&1; \
    if ((ps)==0){ \
        short* d_ = &lds[par_*8192 + wbase]; \
        gll16(aSrc +        (long)(kt)*64, d_); \
        gll16(aSrc +   rj + (long)(kt)*64, d_ + 2048); \
        gll16(aSrc + 2*rj + (long)(kt)*64, d_ + 4096); \
        gll16(aSrc + 3*rj + (long)(kt)*64, d_ + 6144); \
    } else { \
        short* d_ = &lds[16384 + par_*12288 + wbase]; \
        gll16(bSrc +        (long)(kt)*64, d_); \
        gll16(bSrc +   rj + (long)(kt)*64, d_ + 2048); \
        gll16(bSrc + 2*rj + (long)(kt)*64, d_ + 4096); \
        gll16(bSrc + 3*rj + (long)(kt)*64, d_ + 6144); \
        gll16(bSrc + 4*rj + (long)(kt)*64, d_ + 8192); \
        gll16(bSrc + 5*rj + (long)(kt)*64, d_ + 10240); \
    } }

    STAGE(0,0); STAGE(0,1);

    for (int kt=0; kt<NT; ++kt){
        int pA  = (kt&1)*8192;
        int pBb = 16384 + (kt&1)*12288;
        bool pf = (kt+1 < NT);
        if (pf){
            STAGE(kt+1, 0);
            asm volatile("s_waitcnt vmcnt(4)" ::: "memory");
        } else {
            asm volatile("s_waitcnt vmcnt(0)" ::: "memory");
        }
        __builtin_amdgcn_s_barrier();
        __builtin_amdgcn_sched_barrier(0);
        if (pf) STAGE(kt+1, 1);
        short8_t af0[8], af1[8], bf0[3], bf1[3];
        #pragma unroll
        for (int i=0;i<8;i++){
            af0[i] = *(const short8_t*)&lds[pA + aFrag + i*1024 + slotK0];
            af1[i] = *(const short8_t*)&lds[pA + aFrag + i*1024 + slotK1];
        }
        #pragma unroll
        for (int j=0;j<3;j++){
            bf0[j] = *(const short8_t*)&lds[pBb + bFrag + j*1024 + slotK0];
            bf1[j] = *(const short8_t*)&lds[pBb + bFrag + j*1024 + slotK1];
        }
        __builtin_amdgcn_s_setprio(1);
        #pragma unroll
        for (int i=0;i<8;i++)
            #pragma unroll
            for (int j=0;j<3;j++)
                acc[i][j] = __builtin_amdgcn_mfma_f32_16x16x32_bf16(af0[i], bf0[j], acc[i][j], 0, 0, 0);
        #pragma unroll
        for (int i=0;i<8;i++)
            #pragma unroll
            for (int j=0;j<3;j++)
                acc[i][j] = __builtin_amdgcn_mfma_f32_16x16x32_bf16(af1[i], bf1[j], acc[i][j], 0, 0, 0);
        __builtin_amdgcn_s_setprio(0);
        __builtin_amdgcn_sched_barrier(0);
        __builtin_amdgcn_s_barrier();
        __builtin_amdgcn_sched_barrier(0);
    }
#undef STAGE

    int rbase = m0 + g*4;
    int cbase = n0 + wn + frow;
    float bv0 = bias[cbase], bv1 = bias[cbase+16], bv2 = bias[cbase+32];
    #pragma unroll
    for (int i=0;i<8;i++){
        #pragma unroll
        for (int r=0;r<4;r++){
            int row = rbase + i*16 + r;
            float v0 = acc[i][0][r] + bv0;
            float v1 = acc[i][1][r] + bv1;
            float v2 = acc[i][2][r] + bv2;
            if (MODE == 0){
                bf16* o_ = outBf + (long)row*Nd + cbase;
                o_[0]  = __float2bfloat16(v0);
                o_[16] = __float2bfloat16(v1);
                o_[32] = __float2bfloat16(v2);
            } else if (MODE == 1){
                bf16* o_ = outBf + (long)row*Nd + cbase;
                o_[0]  = __float2bfloat16(gelu_f(v0));
                o_[16] = __float2bfloat16(gelu_f(v1));
                o_[32] = __float2bfloat16(gelu_f(v2));
            } else {
                int bb = row >> 9;
                const float* gp = gate + (long)bb*gateStride + cbase;
                float* hp = hres + (long)row*768 + cbase;
                hp[0]  += gp[0]  * v0;
                hp[16] += gp[16] * v1;
                hp[32] += gp[32] * v2;
            }
        }
    }
}

// ---------------- 256x128 deep-pipelined bf16 MFMA GEMM ----------------
// 512 thr = 8 waves 4M x 2N (64x64/wave). BK=64, NT=Kd/64.
// LDS 128 KiB: A TRIPLE-buffered (3 x 32 KB, slot kt%3) staged TWO tiles
// ahead (lead ~1.5-2 tiles >= HBM latency); B double-buffered (2 x 16 KB,
// slot kt&1) staged one tile ahead (L2-hot weights). Steady-state
// vmcnt(4) at tile end waits only on loads issued >=1.5 tiles earlier ->
// latency-stall-free at 1 block/CU (fix for the round-1/2 failure).
template<int MODE>
__global__ __launch_bounds__(512, 1) void gemm256x128_kernel(
    const bf16* __restrict__ A, const bf16* __restrict__ Bw,
    const float* __restrict__ bias, bf16* __restrict__ outBf,
    int Nd, int Kd)
{
    __shared__ __align__(16) short lds[65536];   // 128 KiB
    int tid = threadIdx.x;
    int lane = tid & 63, wave = tid >> 6;
    int frow = lane & 15, g = lane >> 4;
    int wm = wave >> 1, wn = wave & 1;

    // XCD swizzle: ct slowest (B-panel L2-resident per XCD), Mtiles=64
    int bid = blockIdx.x;
    int xcd = bid & 7, wq = bid >> 3;
    int mt = xcd*8 + (wq & 7);
    int ct = wq >> 3;
    int m0 = mt*256, n0 = ct*128;

    const short* Ag = (const short*)A;
    const short* Bg = (const short*)Bw;
    int r0 = tid >> 3, s0 = (tid & 7) ^ (r0 & 7);
    const short* aSrc = Ag + (long)(m0 + r0)*Kd + s0*8;
    const short* bSrc = Bg + (long)(n0 + r0)*Kd + s0*8;
    long r64 = (long)64*Kd;
    int wb = wave*512;

    int aRd = (wm*64 + frow)*64;
    int bRd = (wn*64 + frow)*64;
    int slotK0 = (g ^ (frow & 7))*8;
    int slotK1 = ((4+g) ^ (frow & 7))*8;

    f32x4 acc[4][4];
    #pragma unroll
    for (int i=0;i<4;i++)
        #pragma unroll
        for (int j=0;j<4;j++) acc[i][j] = (f32x4){0.f,0.f,0.f,0.f};

    int NT = Kd >> 6;

// stage A-tile quarter-pairs: qq in {0,2}; 2 gll16 (rows qq*64..qq*64+127)
#define STA2(kt, qq) { \
    short* dA_ = &lds[((kt)%3)*16384 + (qq)*4096 + wb]; \
    const short* sA_ = aSrc + (long)(qq)*r64 + (long)(kt)*64; \
    gll16(sA_, dA_); gll16(sA_ + r64, dA_ + 4096); }
// stage full B-tile (128 rows): 2 gll16
#define STB(kt) { \
    short* dB_ = &lds[49152 + ((kt)&1)*8192 + wb]; \
    const short* sB_ = bSrc + (long)(kt)*64; \
    gll16(sB_, dB_); gll16(sB_ + r64, dB_ + 4096); }

    // prologue: A(0) x4, B(0) x2, A(1) x4 ; wait 6 oldest -> A0,B0 resident
    STA2(0,0); STA2(0,2); STB(0); STA2(1,0); STA2(1,2);
    asm volatile("s_waitcnt vmcnt(4)" ::: "memory");
    __builtin_amdgcn_s_barrier();
    __builtin_amdgcn_sched_barrier(0);

    for (int kt=0; kt<NT; ++kt){
        int pA = (kt%3)*16384;
        int pB = 49152 + (kt&1)*8192;
        bool p1 = (kt+1 < NT), p2 = (kt+2 < NT);

        short8_t af[4], bfr[4];
        // ---- k-half 0
        #pragma unroll
        for (int i=0;i<4;i++) af[i]  = *(const short8_t*)&lds[pA + aRd + i*1024 + slotK0];
        #pragma unroll
        for (int j=0;j<4;j++) bfr[j] = *(const short8_t*)&lds[pB + bRd + j*1024 + slotK0];
        if (p1) STB(kt+1);
        if (p2) STA2(kt+2, 0);
        __builtin_amdgcn_s_setprio(1);
        #pragma unroll
        for (int i=0;i<4;i++)
            #pragma unroll
            for (int j=0;j<4;j++)
                acc[i][j] = __builtin_amdgcn_mfma_f32_16x16x32_bf16(af[i], bfr[j], acc[i][j], 0, 0, 0);
        __builtin_amdgcn_s_setprio(0);
        // ---- k-half 1
        #pragma unroll
        for (int i=0;i<4;i++) af[i]  = *(const short8_t*)&lds[pA + aRd + i*1024 + slotK1];
        #pragma unroll
        for (int j=0;j<4;j++) bfr[j] = *(const short8_t*)&lds[pB + bRd + j*1024 + slotK1];
        if (p2) STA2(kt+2, 2);
        __builtin_amdgcn_s_setprio(1);
        #pragma unroll
        for (int i=0;i<4;i++)
            #pragma unroll
            for (int j=0;j<4;j++)
                acc[i][j] = __builtin_amdgcn_mfma_f32_16x16x32_bf16(af[i], bfr[j], acc[i][j], 0, 0, 0);
        __builtin_amdgcn_s_setprio(0);
        __builtin_amdgcn_sched_barrier(0);
        // drain: A(kt+1)+B(kt+1) resident for next tile; A(kt+2) stays in flight
        if (p2)      { asm volatile("s_waitcnt vmcnt(4)" ::: "memory"); }
        else if (p1) { asm volatile("s_waitcnt vmcnt(0)" ::: "memory"); }
        if (p1){
            __builtin_amdgcn_s_barrier();
            __builtin_amdgcn_sched_barrier(0);
        }
    }
#undef STA2
#undef STB

    // epilogue: rows rb + i*16 + r, cols cb + j*16
    int rb = m0 + wm*64 + g*4;
    int cb = n0 + wn*64 + frow;
    float bv[4];
    #pragma unroll
    for (int j=0;j<4;j++) bv[j] = bias[cb + j*16];
    #pragma unroll
    for (int i=0;i<4;i++){
        #pragma unroll
        for (int r=0;r<4;r++){
            int row = rb + i*16 + r;
            bf16* o_ = outBf + (long)row*Nd + cb;
            #pragma unroll
            for (int j=0;j<4;j++){
                float v = acc[i][j][r] + bv[j];
                if (MODE == 1) v = gelu_f(v);
                o_[j*16] = __float2bfloat16(v);
            }
        }
    }
}

// ---------------- MFMA flash attention ----------------
__global__ __launch_bounds__(256) void attn_mfma_kernel(
    const bf16* __restrict__ qkv, const int* __restrict__ mask, bf16* __restrict__ o)
{
    __shared__ __align__(16) short Ks[64][72];
    __shared__ __align__(16) short Vt[64][72];
    __shared__ __align__(16) short Ps[4][16][72];
    __shared__ float maskf[512];
    int tid = threadIdx.x, lane = tid & 63, wave = tid >> 6;
    int qt = blockIdx.x, hh = blockIdx.y, b = blockIdx.z;
    long base = (long)b * 512 * 2304;
    const short* qkvs = (const short*)qkv;

    maskf[tid]       = mask[b*512 + tid]       ? -1e30f : 0.0f;
    maskf[tid + 256] = mask[b*512 + tid + 256] ? -1e30f : 0.0f;

    int c = lane & 15, g = lane >> 4;
    int qrowA = qt*64 + wave*16 + c;
    const short* qptr = qkvs + base + (long)qrowA*2304 + hh*64 + g*8;
    short8_t qa0 = *(const short8_t*)qptr;
    short8_t qa1 = *(const short8_t*)(qptr + 32);

    f32x4 oacc[4];
    #pragma unroll
    for (int j=0;j<4;j++) oacc[j] = (f32x4){0.f,0.f,0.f,0.f};
    float m_r[4], l_r[4];
    #pragma unroll
    for (int r=0;r<4;r++){ m_r[r] = -50.0f; l_r[r] = 0.0f; }

    int kp = (tid & 31)*2, gv = tid >> 5;
    const short* kgbase = qkvs + base + 768  + hh*64;
    const short* vgbase = qkvs + base + 1536 + hh*64 + gv*8;

    for (int kt=0; kt<8; ++kt){
        __syncthreads();
        {
            int v0 = tid, v1 = tid + 256;
            int r0 = v0>>3, c0 = (v0&7)*8, r1 = v1>>3, c1 = (v1&7)*8;
            *(short8_t*)&Ks[r0][c0] = *(const short8_t*)(kgbase + (long)(kt*64 + r0)*2304 + c0);
            *(short8_t*)&Ks[r1][c1] = *(const short8_t*)(kgbase + (long)(kt*64 + r1)*2304 + c1);
            short8_t va = *(const short8_t*)(vgbase + (long)(kt*64 + kp    )*2304);
            short8_t vb = *(const short8_t*)(vgbase + (long)(kt*64 + kp + 1)*2304);
            #pragma unroll
            for (int e=0;e<8;e++){
                unsigned int pack = (unsigned int)(unsigned short)va[e]
                                  | ((unsigned int)(unsigned short)vb[e] << 16);
                *(unsigned int*)&Vt[gv*8 + e][kp] = pack;
            }
        }
        __syncthreads();
        f32x4 s[4];
        #pragma unroll
        for (int j=0;j<4;j++){
            short8_t kb0 = *(const short8_t*)&Ks[j*16 + c][g*8];
            short8_t kb1 = *(const short8_t*)&Ks[j*16 + c][g*8 + 32];
            f32x4 z = (f32x4){0.f,0.f,0.f,0.f};
            z = __builtin_amdgcn_mfma_f32_16x16x32_bf16(qa0, kb0, z, 0, 0, 0);
            z = __builtin_amdgcn_mfma_f32_16x16x32_bf16(qa1, kb1, z, 0, 0, 0);
            s[j] = z;
        }
        #pragma unroll
        for (int j=0;j<4;j++){
            float mbj = maskf[kt*64 + j*16 + c];
            #pragma unroll
            for (int r=0;r<4;r++) s[j][r] = s[j][r]*0.125f + mbj;
        }
        #pragma unroll
        for (int r=0;r<4;r++){
            float tm = fmaxf(fmaxf(s[0][r], s[1][r]), fmaxf(s[2][r], s[3][r]));
            #pragma unroll
            for (int o_=1;o_<16;o_<<=1) tm = fmaxf(tm, __shfl_xor(tm, o_, 64));
            float mn  = fmaxf(m_r[r], tm);
            float fac = __expf(m_r[r] - mn);
            m_r[r] = mn;
            float ls = l_r[r]*fac;
            #pragma unroll
            for (int j=0;j<4;j++){
                float p = __expf(s[j][r] - mn);
                s[j][r] = p;
                ls += p;
            }
            l_r[r] = ls;
            #pragma unroll
            for (int j=0;j<4;j++) oacc[j][r] *= fac;
        }
        #pragma unroll
        for (int j=0;j<4;j++)
            #pragma unroll
            for (int r=0;r<4;r++)
                *(bf16*)&Ps[wave][g*4 + r][j*16 + c] = __float2bfloat16(s[j][r]);
        short8_t pa0 = *(const short8_t*)&Ps[wave][c][g*8];
        short8_t pa1 = *(const short8_t*)&Ps[wave][c][g*8 + 32];
        #pragma unroll
        for (int j=0;j<4;j++){
            short8_t vb0 = *(const short8_t*)&Vt[j*16 + c][g*8];
            short8_t vb1 = *(const short8_t*)&Vt[j*16 + c][g*8 + 32];
            oacc[j] = __builtin_amdgcn_mfma_f32_16x16x32_bf16(pa0, vb0, oacc[j], 0, 0, 0);
            oacc[j] = __builtin_amdgcn_mfma_f32_16x16x32_bf16(pa1, vb1, oacc[j], 0, 0, 0);
        }
    }
    #pragma unroll
    for (int r=0;r<4;r++){
        float lt = l_r[r];
        #pragma unroll
        for (int o_=1;o_<16;o_<<=1) lt += __shfl_xor(lt, o_, 64);
        l_r[r] = 1.0f / lt;
    }
    int qrowC = qt*64 + wave*16 + g*4;
    bf16* orow = o + ((long)b*512 + qrowC)*768 + hh*64;
    #pragma unroll
    for (int r=0;r<4;r++)
        #pragma unroll
        for (int j=0;j<4;j++)
            orow[(long)r*768 + j*16 + c] = __float2bfloat16(oacc[j][r] * l_r[r]);
}

// ---------------- final: out = xm @ W_out ----------------
__global__ __launch_bounds__(256) void outdot_kernel(
    const bf16* __restrict__ xm, const float* __restrict__ Wout, float* __restrict__ out)
{
    int tid=threadIdx.x, lane=tid&63, wave=tid>>6;
    long row = (long)blockIdx.x*4 + wave;
    const bf16* xr = xm + row*768;
    float acc = 0.f;
    #pragma unroll
    for (int i=0;i<12;i++){ int d = lane + i*64; acc = fmaf(__bfloat162float(xr[d]), Wout[d], acc); }
    #pragma unroll
    for (int o_=1;o_<64;o_<<=1) acc += __shfl_xor(acc, o_, 64);
    if (lane==0) out[row] = acc;
}

extern "C" void kernel_launch(void* const* d_in, const int* in_sizes, int n_in,
                              void* d_out, int out_size, void* d_ws, size_t ws_size,
                              hipStream_t stream)
{
    const float* x      = (const float*)d_in[0];
    const float* W_xemb = (const float*)d_in[1];
    const float* b_xemb = (const float*)d_in[2];
    const float* ds_t   = (const float*)d_in[3];
    const float* sg_t   = (const float*)d_in[4];
    const float* Wqkv   = (const float*)d_in[5];
    const float* bqkv   = (const float*)d_in[6];
    const float* Wo     = (const float*)d_in[7];
    const float* bo     = (const float*)d_in[8];
    const float* W1     = (const float*)d_in[9];
    const float* b1     = (const float*)d_in[10];
    const float* W2     = (const float*)d_in[11];
    const float* b2     = (const float*)d_in[12];
    const float* Wada   = (const float*)d_in[13];
    const float* bada   = (const float*)d_in[14];
    const float* Wada_f = (const float*)d_in[15];
    const float* bada_f = (const float*)d_in[16];
    const float* W_out  = (const float*)d_in[17];
    const int* dataset  = (const int*)d_in[18];
    const int* sgroup   = (const int*)d_in[19];
    const int* mask     = (const int*)d_in[20];
    float* out = (float*)d_out;

    char* ws = (char*)d_ws;
    size_t off = 0;
    auto alloc = [&](size_t bytes)->void*{
        void* p = ws + off; off += (bytes + 255) & ~(size_t)255; return p; };
    float* h     = (float*)alloc((size_t)M_*768*4);         // 50.3 MB
    float* csilu = (float*)alloc((size_t)32*768*4);
    float* modsA = (float*)alloc((size_t)12*32*4608*4);     // 7.1 MB
    float* modsF = (float*)alloc((size_t)32*1536*4);
    bf16*  xm    = (bf16*) alloc((size_t)M_*768*2);         // 25.2 MB
    bf16*  wbuf  = (bf16*) alloc((size_t)7077888*2);        // 14.2 MB per-layer bf16 weights
    bf16*  big   = (bf16*) alloc((size_t)M_*3072*2);        // 100.7 MB (qkv / y1 / mods partials)
    bf16* qkvb = big;
    bf16* y1   = big;
    float* partA = (float*)big;                      // 56.6 MB (pre-loop only)
    float* partF = partA + (size_t)8*12*32*4608;
    bf16* wqT = wbuf;                 // [2304][768]
    bf16* woT = wqT + 2304*768;       // [768][768]
    bf16* w1T = woT + 768*768;        // [3072][768]
    bf16* w2T = w1T + 3072*768;       // [768][3072]

    embed_kernel<<<49152, 256, 0, stream>>>(x, W_xemb, b_xemb, h);
    csilu_kernel<<<96, 256, 0, stream>>>(ds_t, sg_t, dataset, sgroup, csilu);
    mods_part_kernel<<<dim3(9,12,16), 256, 0, stream>>>(csilu, Wada, partA, 2304, (long)768*4608);
    mods_reduce_kernel<<<6912, 256, 0, stream>>>(partA, bada, modsA, 4608, 12);
    mods_part_kernel<<<dim3(3,1,16), 256, 0, stream>>>(csilu, Wada_f, partF, 768, 0);
    mods_reduce_kernel<<<192, 256, 0, stream>>>(partF, bada_f, modsF, 1536, 1);

    for (int l=0; l<12; ++l){
        const float* modsL = modsA + (long)l*32*4608;
        transpose4_kernel<<<6912, 256, 0, stream>>>(
            Wqkv + (long)l*768*2304, Wo + (long)l*768*768,
            W1 + (long)l*768*3072,  W2 + (long)l*3072*768,
            wqT, woT, w1T, w2T);

        ln_mod_kernel<<<4096, 256, 0, stream>>>(h, modsL + 0*768, modsL + 1*768, 4608, xm);
        gemm256x128_kernel<0><<<1152, 512, 0, stream>>>(xm, wqT, bqkv + l*2304, qkvb, 2304, 768);
        attn_mfma_kernel<<<dim3(8, 12, 32), 256, 0, stream>>>(qkvb, mask, xm);
        gemm128_kernel<2><<<dim3(4, 128), 256, 0, stream>>>(xm, woT, bo + l*768, nullptr,
                                                            h, modsL + 2*768, 768, 768, 4608);
        ln_mod_kernel<<<4096, 256, 0, stream>>>(h, modsL + 3*768, modsL + 4*768, 4608, xm);
        gemm256x128_kernel<1><<<1536, 512, 0, stream>>>(xm, w1T, b1 + l*3072, y1, 3072, 768);
        gemm128_kernel<2><<<dim3(4, 128), 256, 0, stream>>>(y1, w2T, b2 + l*768, nullptr,
                                                            h, modsL + 5*768, 768, 3072, 4608);
    }
    ln_mod_kernel<<<4096, 256, 0, stream>>>(h, modsF + 0, modsF + 768, 1536, xm);
    outdot_kernel<<<4096, 256, 0, stream>>>(xm, W_out, out);
}

// Round 5
// 4836.617 us; speedup vs baseline: 1.0668x; 1.0668x over previous
//
#include <hip/hip_runtime.h>
#include <hip/hip_bf16.h>

#define B_   32
#define N_   512
#define D_   768
#define H_   12
#define HID_ 3072
#define L_   12
#define M_   (B_*N_)   // 16384

typedef __attribute__((ext_vector_type(8))) short short8_t;
typedef __attribute__((ext_vector_type(4))) short short4_t;
typedef __attribute__((ext_vector_type(4))) float f32x4;
typedef __hip_bfloat16 bf16;

__device__ __forceinline__ void gll16(const void* g, void* l){
    __builtin_amdgcn_global_load_lds((const __attribute__((address_space(1))) void*)g,
                                     (__attribute__((address_space(3))) void*)l, 16, 0, 0);
}

// ---------------- positional table: ptab[n][d], 512x768 ----------------
__global__ __launch_bounds__(256) void pos_kernel(float* __restrict__ ptab)
{
    int idx = blockIdx.x*256 + threadIdx.x;   // < 512*768
    int d = idx % 768, n = idx / 768;
    int K = (d < 384) ? d : d - 384;
    float ang = (float)n * 3.14159265358979323846f * expf(-(2.0f*(float)K/768.0f) * 7.624618986159398f);
    ptab[idx] = (d < 384) ? sinf(ang) : cosf(ang);
}

// ---------------- embedding: h = x@W_xemb + b + ptab ----------------
__global__ __launch_bounds__(256) void embed_kernel(
    const float* __restrict__ x, const float* __restrict__ Wx,
    const float* __restrict__ bx, const float* __restrict__ ptab,
    float* __restrict__ h)
{
    long idx = (long)blockIdx.x * 256 + threadIdx.x;   // < 16384*768
    int d = (int)(idx % 768);
    long m = idx / 768;
    int n = (int)(m % 512);
    float acc = bx[d] + ptab[n*768 + d];
    const float* xr = x + m * 16;
    #pragma unroll
    for (int k = 0; k < 16; ++k) acc = fmaf(xr[k], Wx[k*768 + d], acc);
    h[idx] = acc;
}

// ---------------- c_silu = silu(ds_table[dataset] + sg_table[spacegroup]) ----------------
__global__ __launch_bounds__(256) void csilu_kernel(
    const float* __restrict__ ds_t, const float* __restrict__ sg_t,
    const int* __restrict__ dataset, const int* __restrict__ sg, float* __restrict__ out)
{
    int idx = blockIdx.x*256 + threadIdx.x;   // 32*768
    int b = idx / 768, d = idx % 768;
    float c = ds_t[dataset[b]*768 + d] + sg_t[sg[b]*768 + d];
    out[idx] = c / (1.0f + expf(-c));
}

// ---------------- mods partials v2: 16-b groups, csilu in LDS ----------------
__global__ __launch_bounds__(256) void mods_part_kernel(
    const float* __restrict__ csilu, const float* __restrict__ W,
    float* __restrict__ part, int Nd2, long wLayerStride)
{
    __shared__ float cs[16][96];
    int n2 = blockIdx.x*256 + threadIdx.x;
    int l = blockIdx.y, z = blockIdx.z;
    int kz = z >> 1, bg = z & 1;
    int L = gridDim.y;
    for (int t = threadIdx.x; t < 16*96; t += 256){
        int bb = t / 96, kk = t - bb*96;
        cs[bb][kk] = csilu[(bg*16 + bb)*768 + kz*96 + kk];
    }
    __syncthreads();
    const float2* Wl = (const float2*)(W + (long)l*wLayerStride);
    float2 acc[16];
    #pragma unroll
    for (int b=0;b<16;b++) acc[b] = make_float2(0.f, 0.f);
    for (int k=0;k<96;++k){
        float2 wv = Wl[(long)(kz*96 + k)*Nd2 + n2];
        #pragma unroll
        for (int b=0;b<16;b++){
            float c = cs[b][k];
            acc[b].x = fmaf(c, wv.x, acc[b].x);
            acc[b].y = fmaf(c, wv.y, acc[b].y);
        }
    }
    float2* pp = (float2*)part + ((long)(kz*L + l)*32 + bg*16)*Nd2 + n2;
    #pragma unroll
    for (int b=0;b<16;b++) pp[(long)b*Nd2] = acc[b];
}

__global__ __launch_bounds__(256) void mods_reduce_kernel(
    const float* __restrict__ part, const float* __restrict__ bias,
    float* __restrict__ out, int Nd, int L)
{
    long idx = (long)blockIdx.x*256 + threadIdx.x;  // over L*32*Nd
    int n = (int)(idx % Nd);
    long r = idx / Nd;
    int b = (int)(r & 31);
    int l = (int)(r >> 5);
    float s = bias[(long)l*Nd + n];
    #pragma unroll
    for (int z=0;z<8;z++) s += part[((long)(z*L + l)*32 + b)*Nd + n];
    out[idx] = s;
}

// ---------------- fused per-layer weight transpose fp32 [K][N] -> bf16 [N][K] ----------------
__global__ __launch_bounds__(256) void transpose4_kernel(
    const float* __restrict__ Wqkv, const float* __restrict__ Wo,
    const float* __restrict__ W1,  const float* __restrict__ W2,
    bf16* __restrict__ wqT, bf16* __restrict__ woT,
    bf16* __restrict__ w1T, bf16* __restrict__ w2T)
{
    __shared__ float t[32][33];
    int tt = blockIdx.x;
    const float* src; bf16* dst; int K, Nd, nx;
    if (tt < 1728){ src=Wqkv; dst=wqT; K=768; Nd=2304; nx=72; }
    else if (tt < 2304){ src=Wo; dst=woT; K=768; Nd=768; nx=24; tt -= 1728; }
    else if (tt < 4608){ src=W1; dst=w1T; K=768; Nd=3072; nx=96; tt -= 2304; }
    else { src=W2; dst=w2T; K=3072; Nd=768; nx=24; tt -= 4608; }
    int n0 = (tt % nx)*32, k0 = (tt / nx)*32;
    int tx = threadIdx.x & 31, ty = threadIdx.x >> 5;   // 32 x 8
    #pragma unroll
    for (int j=0;j<4;j++)
        t[ty + j*8][tx] = src[(long)(k0 + ty + j*8)*Nd + n0 + tx];
    __syncthreads();
    #pragma unroll
    for (int j=0;j<4;j++)
        dst[(long)(n0 + ty + j*8)*K + k0 + tx] = __float2bfloat16(t[tx][ty + j*8]);
}

// ---------------- LayerNorm + modulate -> bf16 (wave-per-row, float4) ----------------
__global__ __launch_bounds__(256) void ln_mod_kernel(
    const float* __restrict__ h, const float* __restrict__ shiftB,
    const float* __restrict__ scaleB, int modsStride, bf16* __restrict__ out)
{
    int wave = threadIdx.x >> 6, lane = threadIdx.x & 63;
    long row = (long)blockIdx.x*4 + wave;
    int b = (int)(row >> 9);
    const float4* xr = (const float4*)(h + row*768);
    float4 v[3];
    float s = 0.f, ss = 0.f;
    #pragma unroll
    for (int i=0;i<3;i++){
        v[i] = xr[lane + i*64];
        s  += v[i].x + v[i].y + v[i].z + v[i].w;
        ss += v[i].x*v[i].x + v[i].y*v[i].y + v[i].z*v[i].z + v[i].w*v[i].w;
    }
    #pragma unroll
    for (int o=1;o<64;o<<=1){ s += __shfl_xor(s,o,64); ss += __shfl_xor(ss,o,64); }
    float mean = s * (1.0f/768.0f);
    float var  = ss * (1.0f/768.0f) - mean*mean;
    float rstd = rsqrtf(var + 1e-6f);
    const float4* sh4 = (const float4*)(shiftB + (long)b*modsStride);
    const float4* sc4 = (const float4*)(scaleB + (long)b*modsStride);
    short4_t* orow = (short4_t*)(out + row*768);
    #pragma unroll
    for (int i=0;i<3;i++){
        float4 sh = sh4[lane + i*64];
        float4 sc = sc4[lane + i*64];
        float o0 = (v[i].x-mean)*rstd*(1.f+sc.x) + sh.x;
        float o1 = (v[i].y-mean)*rstd*(1.f+sc.y) + sh.y;
        float o2 = (v[i].z-mean)*rstd*(1.f+sc.z) + sh.z;
        float o3 = (v[i].w-mean)*rstd*(1.f+sc.w) + sh.w;
        bf16 b0 = __float2bfloat16(o0), b1 = __float2bfloat16(o1);
        bf16 b2 = __float2bfloat16(o2), b3 = __float2bfloat16(o3);
        short4_t pk;
        pk[0] = *(short*)&b0; pk[1] = *(short*)&b1;
        pk[2] = *(short*)&b2; pk[3] = *(short*)&b3;
        orow[lane + i*64] = pk;
    }
}

// gelu(tanh approx) via sigmoid identity: 0.5x(1+tanh(z)) = x * sigmoid(2z)
__device__ __forceinline__ float gelu_f(float x){
    float z2 = 1.5957691216057308f * x * (1.0f + 0.044715f*x*x);
    return x / (1.0f + __expf(-z2));
}

// ---------------- 128x192 pipelined bf16 MFMA GEMM (round-3, 4680-verified) ----------------
template<int MODE>
__global__ __launch_bounds__(256, 2) void gemm128_kernel(
    const bf16* __restrict__ A, const bf16* __restrict__ Bw,
    const float* __restrict__ bias, bf16* __restrict__ outBf,
    float* __restrict__ hres, const float* __restrict__ gate,
    int Nd, int Kd, int gateStride)
{
    __shared__ __align__(16) short lds[40960];   // 80 KiB
    int tid = threadIdx.x;
    int lane = tid & 63, wave = tid >> 6;
    int frow = lane & 15, g = lane >> 4;

    int nx = gridDim.x;
    int bid = blockIdx.y * nx + blockIdx.x;
    int xcd = bid & 7;
    int wq  = bid >> 3;
    int mt  = xcd * 16 + (wq & 15);
    int ct  = wq >> 4;
    int m0 = mt * 128, n0 = ct * 192;
    int wn = wave * 48;

    const short* Ag = (const short*)A;
    const short* Bg = (const short*)Bw;
    int r0 = tid >> 3, s0 = (tid & 7) ^ ((tid >> 3) & 7);
    const short* aSrc = Ag + (long)(m0 + r0)*Kd + s0*8;
    const short* bSrc = Bg + (long)(n0 + r0)*Kd + s0*8;
    long rj = (long)32*Kd;
    int wbase = wave*512;

    int aFrag = frow*64;
    int bFrag = (wn + frow)*64;
    int slotK0 = (g ^ (frow & 7))*8;
    int slotK1 = ((4+g) ^ (frow & 7))*8;

    f32x4 acc[8][3];
    #pragma unroll
    for (int i=0;i<8;i++)
        #pragma unroll
        for (int j=0;j<3;j++) acc[i][j] = (f32x4){0.f,0.f,0.f,0.f};

    int NT = Kd >> 6;

#define STAGE(kt, ps) { \
    int par_ = (kt)&1; \
    if ((ps)==0){ \
        short* d_ = &lds[par_*8192 + wbase]; \
        gll16(aSrc +        (long)(kt)*64, d_); \
        gll16(aSrc +   rj + (long)(kt)*64, d_ + 2048); \
        gll16(aSrc + 2*rj + (long)(kt)*64, d_ + 4096); \
        gll16(aSrc + 3*rj + (long)(kt)*64, d_ + 6144); \
    } else { \
        short* d_ = &lds[16384 + par_*12288 + wbase]; \
        gll16(bSrc +        (long)(kt)*64, d_); \
        gll16(bSrc +   rj + (long)(kt)*64, d_ + 2048); \
        gll16(bSrc + 2*rj + (long)(kt)*64, d_ + 4096); \
        gll16(bSrc + 3*rj + (long)(kt)*64, d_ + 6144); \
        gll16(bSrc + 4*rj + (long)(kt)*64, d_ + 8192); \
        gll16(bSrc + 5*rj + (long)(kt)*64, d_ + 10240); \
    } }

    STAGE(0,0); STAGE(0,1);

    for (int kt=0; kt<NT; ++kt){
        int pA  = (kt&1)*8192;
        int pBb = 16384 + (kt&1)*12288;
        bool pf = (kt+1 < NT);
        if (pf){
            STAGE(kt+1, 0);
            asm volatile("s_waitcnt vmcnt(4)" ::: "memory");
        } else {
            asm volatile("s_waitcnt vmcnt(0)" ::: "memory");
        }
        __builtin_amdgcn_s_barrier();
        __builtin_amdgcn_sched_barrier(0);
        if (pf) STAGE(kt+1, 1);
        short8_t af0[8], af1[8], bf0[3], bf1[3];
        #pragma unroll
        for (int i=0;i<8;i++){
            af0[i] = *(const short8_t*)&lds[pA + aFrag + i*1024 + slotK0];
            af1[i] = *(const short8_t*)&lds[pA + aFrag + i*1024 + slotK1];
        }
        #pragma unroll
        for (int j=0;j<3;j++){
            bf0[j] = *(const short8_t*)&lds[pBb + bFrag + j*1024 + slotK0];
            bf1[j] = *(const short8_t*)&lds[pBb + bFrag + j*1024 + slotK1];
        }
        __builtin_amdgcn_s_setprio(1);
        #pragma unroll
        for (int i=0;i<8;i++)
            #pragma unroll
            for (int j=0;j<3;j++)
                acc[i][j] = __builtin_amdgcn_mfma_f32_16x16x32_bf16(af0[i], bf0[j], acc[i][j], 0, 0, 0);
        #pragma unroll
        for (int i=0;i<8;i++)
            #pragma unroll
            for (int j=0;j<3;j++)
                acc[i][j] = __builtin_amdgcn_mfma_f32_16x16x32_bf16(af1[i], bf1[j], acc[i][j], 0, 0, 0);
        __builtin_amdgcn_s_setprio(0);
        __builtin_amdgcn_sched_barrier(0);
        __builtin_amdgcn_s_barrier();
        __builtin_amdgcn_sched_barrier(0);
    }
#undef STAGE

    int rbase = m0 + g*4;
    int cbase = n0 + wn + frow;
    float bv0 = bias[cbase], bv1 = bias[cbase+16], bv2 = bias[cbase+32];
    #pragma unroll
    for (int i=0;i<8;i++){
        #pragma unroll
        for (int r=0;r<4;r++){
            int row = rbase + i*16 + r;
            float v0 = acc[i][0][r] + bv0;
            float v1 = acc[i][1][r] + bv1;
            float v2 = acc[i][2][r] + bv2;
            if (MODE == 0){
                bf16* o_ = outBf + (long)row*Nd + cbase;
                o_[0]  = __float2bfloat16(v0);
                o_[16] = __float2bfloat16(v1);
                o_[32] = __float2bfloat16(v2);
            } else if (MODE == 1){
                bf16* o_ = outBf + (long)row*Nd + cbase;
                o_[0]  = __float2bfloat16(gelu_f(v0));
                o_[16] = __float2bfloat16(gelu_f(v1));
                o_[32] = __float2bfloat16(gelu_f(v2));
            } else {
                int bb = row >> 9;
                const float* gp = gate + (long)bb*gateStride + cbase;
                float* hp = hres + (long)row*768 + cbase;
                hp[0]  += gp[0]  * v0;
                hp[16] += gp[16] * v1;
                hp[32] += gp[32] * v2;
            }
        }
    }
}

// ---------------- 256x256 8-wave m201-cadence GEMM (gemm256v2) ----------------
// 512 thr = 8 waves (2M x 4N interleaved: wave wm rows mh*128+wm*64, wave wn4
// cols nh*128+wn4*32). BK=64, NT=Kd/64. LDS 128 KiB = A[2buf][2half][128][64]
// + B same. Half-tile (ht) = 128 rows = 2 gll16. Per-tile slots s&3:
// 0=A-h0, 1=B-h0, 2=B-h1, 3=A-h1, staged in global ht order s; prologue
// issues s=0..6 (tile0 + tile1:A0,B0,B1), vmcnt(6) -> tile0 resident.
// Loop tile kt stages s = kt*4+7..+10 (ph1: t+1:A1, ph2-4: t+2:A0,B0,B1),
// ONE vmcnt(6) at phase 4 (=> all but newest 3 ht landed => tile kt+1 fully
// resident; 4-7 phase lead covers HBM latency). Quadrant order
// (0,0)->(1,0)->(1,1)->(0,1): ph4 re-uses af0/bf1 from registers (0 ds_reads),
// so no LDS half is re-read after its t+2 overwrite is issued (race-checked
// per half: A0 last read ph1/staged ph2; B0 ph1/ph3; A1 ph2/next-ph1; B1
// ph3/ph4). Tail: kt>=NT-2 uses vmcnt(0) (too few in flight for vmcnt(6)
// to guarantee ordering).
template<int MODE>
__global__ __launch_bounds__(512, 2) void gemm256v2_kernel(
    const bf16* __restrict__ A, const bf16* __restrict__ Bw,
    const float* __restrict__ bias, bf16* __restrict__ outBf,
    int Nd, int Kd)
{
    __shared__ __align__(16) short lds[65536];   // 128 KiB
    int tid = threadIdx.x;
    int lane = tid & 63, wave = tid >> 6;
    int frow = lane & 15, g = lane >> 4;
    int wm = wave >> 2, wn4 = wave & 3;

    int nwg = gridDim.x;
    int bid = blockIdx.x;
    int q8  = nwg >> 3;
    int wgid = (bid & 7) * q8 + (bid >> 3);
    int ntiles = Nd >> 8;
    int mt = wgid / ntiles, ct = wgid - mt*ntiles;
    int m0 = mt * 256, n0 = ct * 256;

    const short* Ag = (const short*)A;
    const short* Bg = (const short*)Bw;
    int r0 = tid >> 3;
    int s0 = (tid & 7) ^ (r0 & 7);
    const short* aSrc = Ag + (long)(m0 + r0)*Kd + s0*8;
    const short* bSrc = Bg + (long)(n0 + r0)*Kd + s0*8;
    long r64 = (long)64*Kd;
    int wb = wave*512;

    int aRd = wm*4096 + frow*64;
    int bRd = wn4*2048 + frow*64;
    int sk0 = (g ^ (frow & 7))*8;
    int sk1 = ((4+g) ^ (frow & 7))*8;

    f32x4 acc[8][4];   // [mh*4+i][nh*2+j]
    #pragma unroll
    for (int i=0;i<8;i++)
        #pragma unroll
        for (int j=0;j<4;j++) acc[i][j] = (f32x4){0.f,0.f,0.f,0.f};

    int NT = Kd >> 6;

#define STA(t, h) { \
    short* d_ = &lds[((t)&1)*16384 + (h)*8192 + wb]; \
    const short* s_ = aSrc + (long)(h)*2*r64 + (long)(t)*64; \
    gll16(s_, d_); gll16(s_ + r64, d_ + 4096); }
#define STB(t, h) { \
    short* d_ = &lds[32768 + ((t)&1)*16384 + (h)*8192 + wb]; \
    const short* s_ = bSrc + (long)(h)*2*r64 + (long)(t)*64; \
    gll16(s_, d_); gll16(s_ + r64, d_ + 4096); }

#define MFMA_Q(mh, nh, AF, BF) { \
    __builtin_amdgcn_s_setprio(1); \
    _Pragma("unroll") \
    for (int kh=0;kh<2;++kh) \
        _Pragma("unroll") \
        for (int i=0;i<4;++i) \
            _Pragma("unroll") \
            for (int j=0;j<2;++j) \
                acc[(mh)*4+i][(nh)*2+j] = __builtin_amdgcn_mfma_f32_16x16x32_bf16( \
                    AF[i][kh], BF[j][kh], acc[(mh)*4+i][(nh)*2+j], 0, 0, 0); \
    __builtin_amdgcn_s_setprio(0); }

    // prologue: ht 0..6 in global order (tile0: A0,B0,B1,A1; tile1: A0,B0,B1)
    STA(0,0); STB(0,0); STB(0,1); STA(0,1);
    STA(1,0); STB(1,0); STB(1,1);
    asm volatile("s_waitcnt vmcnt(6)" ::: "memory");   // oldest 4 ht (=tile0) landed
    __builtin_amdgcn_s_barrier();
    __builtin_amdgcn_sched_barrier(0);

    for (int kt=0; kt<NT; ++kt){
        int pA = (kt&1)*16384;
        int pB = 32768 + (kt&1)*16384;
        short8_t af0[4][2], af1[4][2], bf0[2][2], bf1[2][2];

        // ---- phase 1: Q(0,0); reads A-h0(8) + B-h0(4); stage t+1:A1
        #pragma unroll
        for (int i=0;i<4;++i){
            af0[i][0] = *(const short8_t*)&lds[pA + aRd + i*1024 + sk0];
            af0[i][1] = *(const short8_t*)&lds[pA + aRd + i*1024 + sk1];
        }
        #pragma unroll
        for (int j=0;j<2;++j){
            bf0[j][0] = *(const short8_t*)&lds[pB + bRd + j*1024 + sk0];
            bf0[j][1] = *(const short8_t*)&lds[pB + bRd + j*1024 + sk1];
        }
        if (kt+1 < NT) STA(kt+1, 1);
        asm volatile("s_waitcnt lgkmcnt(8)" ::: "memory");
        __builtin_amdgcn_s_barrier();
        asm volatile("s_waitcnt lgkmcnt(0)" ::: "memory");
        __builtin_amdgcn_sched_barrier(0);
        MFMA_Q(0, 0, af0, bf0);
        __builtin_amdgcn_s_barrier();

        // ---- phase 2: Q(1,0); reads A-h1(8); stage t+2:A0
        #pragma unroll
        for (int i=0;i<4;++i){
            af1[i][0] = *(const short8_t*)&lds[pA + 8192 + aRd + i*1024 + sk0];
            af1[i][1] = *(const short8_t*)&lds[pA + 8192 + aRd + i*1024 + sk1];
        }
        if (kt+2 < NT) STA(kt+2, 0);
        __builtin_amdgcn_s_barrier();
        asm volatile("s_waitcnt lgkmcnt(0)" ::: "memory");
        __builtin_amdgcn_sched_barrier(0);
        MFMA_Q(1, 0, af1, bf0);
        __builtin_amdgcn_s_barrier();

        // ---- phase 3: Q(1,1); reads B-h1(4); stage t+2:B0
        #pragma unroll
        for (int j=0;j<2;++j){
            bf1[j][0] = *(const short8_t*)&lds[pB + 8192 + bRd + j*1024 + sk0];
            bf1[j][1] = *(const short8_t*)&lds[pB + 8192 + bRd + j*1024 + sk1];
        }
        if (kt+2 < NT) STB(kt+2, 0);
        __builtin_amdgcn_s_barrier();
        asm volatile("s_waitcnt lgkmcnt(0)" ::: "memory");
        __builtin_amdgcn_sched_barrier(0);
        MFMA_Q(1, 1, af1, bf1);
        __builtin_amdgcn_s_barrier();

        // ---- phase 4: Q(0,1); no reads (af0/bf1 in regs); stage t+2:B1
        if (kt+2 < NT) STB(kt+2, 1);
        __builtin_amdgcn_s_barrier();
        __builtin_amdgcn_sched_barrier(0);
        MFMA_Q(0, 1, af0, bf1);
        __builtin_amdgcn_sched_barrier(0);
        if (kt < NT-2) { asm volatile("s_waitcnt vmcnt(6)" ::: "memory"); }
        else           { asm volatile("s_waitcnt vmcnt(0)" ::: "memory"); }
        __builtin_amdgcn_s_barrier();
        __builtin_amdgcn_sched_barrier(0);
    }
#undef STA
#undef STB
#undef MFMA_Q

    // epilogue (round-1 verified mapping): cols cb + {0,16,128,144}
    int rb = m0 + wm*64 + g*4;
    int cb = n0 + wn4*32 + frow;
    float bv0 = bias[cb], bv1 = bias[cb+16], bv2 = bias[cb+128], bv3 = bias[cb+144];
    #pragma unroll
    for (int mh=0; mh<2; ++mh){
        #pragma unroll
        for (int i=0;i<4;++i){
            #pragma unroll
            for (int r=0;r<4;++r){
                int row = rb + mh*128 + i*16 + r;
                float v0 = acc[mh*4+i][0][r] + bv0;
                float v1 = acc[mh*4+i][1][r] + bv1;
                float v2 = acc[mh*4+i][2][r] + bv2;
                float v3 = acc[mh*4+i][3][r] + bv3;
                bf16* o_ = outBf + (long)row*Nd + cb;
                if (MODE == 1){
                    v0 = gelu_f(v0); v1 = gelu_f(v1); v2 = gelu_f(v2); v3 = gelu_f(v3);
                }
                o_[0]   = __float2bfloat16(v0);
                o_[16]  = __float2bfloat16(v1);
                o_[128] = __float2bfloat16(v2);
                o_[144] = __float2bfloat16(v3);
            }
        }
    }
}

// ---------------- MFMA flash attention ----------------
__global__ __launch_bounds__(256) void attn_mfma_kernel(
    const bf16* __restrict__ qkv, const int* __restrict__ mask, bf16* __restrict__ o)
{
    __shared__ __align__(16) short Ks[64][72];
    __shared__ __align__(16) short Vt[64][72];
    __shared__ __align__(16) short Ps[4][16][72];
    __shared__ float maskf[512];
    int tid = threadIdx.x, lane = tid & 63, wave = tid >> 6;
    int qt = blockIdx.x, hh = blockIdx.y, b = blockIdx.z;
    long base = (long)b * 512 * 2304;
    const short* qkvs = (const short*)qkv;

    maskf[tid]       = mask[b*512 + tid]       ? -1e30f : 0.0f;
    maskf[tid + 256] = mask[b*512 + tid + 256] ? -1e30f : 0.0f;

    int c = lane & 15, g = lane >> 4;
    int qrowA = qt*64 + wave*16 + c;
    const short* qptr = qkvs + base + (long)qrowA*2304 + hh*64 + g*8;
    short8_t qa0 = *(const short8_t*)qptr;
    short8_t qa1 = *(const short8_t*)(qptr + 32);

    f32x4 oacc[4];
    #pragma unroll
    for (int j=0;j<4;j++) oacc[j] = (f32x4){0.f,0.f,0.f,0.f};
    float m_r[4], l_r[4];
    #pragma unroll
    for (int r=0;r<4;r++){ m_r[r] = -50.0f; l_r[r] = 0.0f; }

    int kp = (tid & 31)*2, gv = tid >> 5;
    const short* kgbase = qkvs + base + 768  + hh*64;
    const short* vgbase = qkvs + base + 1536 + hh*64 + gv*8;

    for (int kt=0; kt<8; ++kt){
        __syncthreads();
        {
            int v0 = tid, v1 = tid + 256;
            int r0 = v0>>3, c0 = (v0&7)*8, r1 = v1>>3, c1 = (v1&7)*8;
            *(short8_t*)&Ks[r0][c0] = *(const short8_t*)(kgbase + (long)(kt*64 + r0)*2304 + c0);
            *(short8_t*)&Ks[r1][c1] = *(const short8_t*)(kgbase + (long)(kt*64 + r1)*2304 + c1);
            short8_t va = *(const short8_t*)(vgbase + (long)(kt*64 + kp    )*2304);
            short8_t vb = *(const short8_t*)(vgbase + (long)(kt*64 + kp + 1)*2304);
            #pragma unroll
            for (int e=0;e<8;e++){
                unsigned int pack = (unsigned int)(unsigned short)va[e]
                                  | ((unsigned int)(unsigned short)vb[e] << 16);
                *(unsigned int*)&Vt[gv*8 + e][kp] = pack;
            }
        }
        __syncthreads();
        f32x4 s[4];
        #pragma unroll
        for (int j=0;j<4;j++){
            short8_t kb0 = *(const short8_t*)&Ks[j*16 + c][g*8];
            short8_t kb1 = *(const short8_t*)&Ks[j*16 + c][g*8 + 32];
            f32x4 z = (f32x4){0.f,0.f,0.f,0.f};
            z = __builtin_amdgcn_mfma_f32_16x16x32_bf16(qa0, kb0, z, 0, 0, 0);
            z = __builtin_amdgcn_mfma_f32_16x16x32_bf16(qa1, kb1, z, 0, 0, 0);
            s[j] = z;
        }
        #pragma unroll
        for (int j=0;j<4;j++){
            float mbj = maskf[kt*64 + j*16 + c];
            #pragma unroll
            for (int r=0;r<4;r++) s[j][r] = s[j][r]*0.125f + mbj;
        }
        #pragma unroll
        for (int r=0;r<4;r++){
            float tm = fmaxf(fmaxf(s[0][r], s[1][r]), fmaxf(s[2][r], s[3][r]));
            #pragma unroll
            for (int o_=1;o_<16;o_<<=1) tm = fmaxf(tm, __shfl_xor(tm, o_, 64));
            float mn  = fmaxf(m_r[r], tm);
            float fac = __expf(m_r[r] - mn);
            m_r[r] = mn;
            float ls = l_r[r]*fac;
            #pragma unroll
            for (int j=0;j<4;j++){
                float p = __expf(s[j][r] - mn);
                s[j][r] = p;
                ls += p;
            }
            l_r[r] = ls;
            #pragma unroll
            for (int j=0;j<4;j++) oacc[j][r] *= fac;
        }
        #pragma unroll
        for (int j=0;j<4;j++)
            #pragma unroll
            for (int r=0;r<4;r++)
                *(bf16*)&Ps[wave][g*4 + r][j*16 + c] = __float2bfloat16(s[j][r]);
        short8_t pa0 = *(const short8_t*)&Ps[wave][c][g*8];
        short8_t pa1 = *(const short8_t*)&Ps[wave][c][g*8 + 32];
        #pragma unroll
        for (int j=0;j<4;j++){
            short8_t vb0 = *(const short8_t*)&Vt[j*16 + c][g*8];
            short8_t vb1 = *(const short8_t*)&Vt[j*16 + c][g*8 + 32];
            oacc[j] = __builtin_amdgcn_mfma_f32_16x16x32_bf16(pa0, vb0, oacc[j], 0, 0, 0);
            oacc[j] = __builtin_amdgcn_mfma_f32_16x16x32_bf16(pa1, vb1, oacc[j], 0, 0, 0);
        }
    }
    #pragma unroll
    for (int r=0;r<4;r++){
        float lt = l_r[r];
        #pragma unroll
        for (int o_=1;o_<16;o_<<=1) lt += __shfl_xor(lt, o_, 64);
        l_r[r] = 1.0f / lt;
    }
    int qrowC = qt*64 + wave*16 + g*4;
    bf16* orow = o + ((long)b*512 + qrowC)*768 + hh*64;
    #pragma unroll
    for (int r=0;r<4;r++)
        #pragma unroll
        for (int j=0;j<4;j++)
            orow[(long)r*768 + j*16 + c] = __float2bfloat16(oacc[j][r] * l_r[r]);
}

// ---------------- final: out = xm @ W_out ----------------
__global__ __launch_bounds__(256) void outdot_kernel(
    const bf16* __restrict__ xm, const float* __restrict__ Wout, float* __restrict__ out)
{
    int tid=threadIdx.x, lane=tid&63, wave=tid>>6;
    long row = (long)blockIdx.x*4 + wave;
    const bf16* xr = xm + row*768;
    float acc = 0.f;
    #pragma unroll
    for (int i=0;i<12;i++){ int d = lane + i*64; acc = fmaf(__bfloat162float(xr[d]), Wout[d], acc); }
    #pragma unroll
    for (int o_=1;o_<64;o_<<=1) acc += __shfl_xor(acc, o_, 64);
    if (lane==0) out[row] = acc;
}

extern "C" void kernel_launch(void* const* d_in, const int* in_sizes, int n_in,
                              void* d_out, int out_size, void* d_ws, size_t ws_size,
                              hipStream_t stream)
{
    const float* x      = (const float*)d_in[0];
    const float* W_xemb = (const float*)d_in[1];
    const float* b_xemb = (const float*)d_in[2];
    const float* ds_t   = (const float*)d_in[3];
    const float* sg_t   = (const float*)d_in[4];
    const float* Wqkv   = (const float*)d_in[5];
    const float* bqkv   = (const float*)d_in[6];
    const float* Wo     = (const float*)d_in[7];
    const float* bo     = (const float*)d_in[8];
    const float* W1     = (const float*)d_in[9];
    const float* b1     = (const float*)d_in[10];
    const float* W2     = (const float*)d_in[11];
    const float* b2     = (const float*)d_in[12];
    const float* Wada   = (const float*)d_in[13];
    const float* bada   = (const float*)d_in[14];
    const float* Wada_f = (const float*)d_in[15];
    const float* bada_f = (const float*)d_in[16];
    const float* W_out  = (const float*)d_in[17];
    const int* dataset  = (const int*)d_in[18];
    const int* sgroup   = (const int*)d_in[19];
    const int* mask     = (const int*)d_in[20];
    float* out = (float*)d_out;

    char* ws = (char*)d_ws;
    size_t off = 0;
    auto alloc = [&](size_t bytes)->void*{
        void* p = ws + off; off += (bytes + 255) & ~(size_t)255; return p; };
    float* h     = (float*)alloc((size_t)M_*768*4);         // 50.3 MB
    float* csilu = (float*)alloc((size_t)32*768*4);
    float* modsA = (float*)alloc((size_t)12*32*4608*4);     // 7.1 MB
    float* modsF = (float*)alloc((size_t)32*1536*4);
    float* ptab  = (float*)alloc((size_t)512*768*4);        // 1.6 MB
    bf16*  xm    = (bf16*) alloc((size_t)M_*768*2);         // 25.2 MB
    bf16*  wbuf  = (bf16*) alloc((size_t)7077888*2);        // 14.2 MB per-layer bf16 weights
    bf16*  big   = (bf16*) alloc((size_t)M_*3072*2);        // 100.7 MB (qkv / y1 / mods partials)
    bf16* qkvb = big;
    bf16* y1   = big;
    float* partA = (float*)big;                      // 56.6 MB (pre-loop only)
    float* partF = partA + (size_t)8*12*32*4608;
    bf16* wqT = wbuf;                 // [2304][768]
    bf16* woT = wqT + 2304*768;       // [768][768]
    bf16* w1T = woT + 768*768;        // [3072][768]
    bf16* w2T = w1T + 3072*768;       // [768][3072]

    pos_kernel<<<1536, 256, 0, stream>>>(ptab);
    embed_kernel<<<49152, 256, 0, stream>>>(x, W_xemb, b_xemb, ptab, h);
    csilu_kernel<<<96, 256, 0, stream>>>(ds_t, sg_t, dataset, sgroup, csilu);
    mods_part_kernel<<<dim3(9,12,16), 256, 0, stream>>>(csilu, Wada, partA, 2304, (long)768*4608);
    mods_reduce_kernel<<<6912, 256, 0, stream>>>(partA, bada, modsA, 4608, 12);
    mods_part_kernel<<<dim3(3,1,16), 256, 0, stream>>>(csilu, Wada_f, partF, 768, 0);
    mods_reduce_kernel<<<192, 256, 0, stream>>>(partF, bada_f, modsF, 1536, 1);

    for (int l=0; l<12; ++l){
        const float* modsL = modsA + (long)l*32*4608;
        transpose4_kernel<<<6912, 256, 0, stream>>>(
            Wqkv + (long)l*768*2304, Wo + (long)l*768*768,
            W1 + (long)l*768*3072,  W2 + (long)l*3072*768,
            wqT, woT, w1T, w2T);

        ln_mod_kernel<<<4096, 256, 0, stream>>>(h, modsL + 0*768, modsL + 1*768, 4608, xm);
        gemm128_kernel<0><<<dim3(12, 128), 256, 0, stream>>>(xm, wqT, bqkv + l*2304, qkvb,
                                                             nullptr, nullptr, 2304, 768, 0);
        attn_mfma_kernel<<<dim3(8, 12, 32), 256, 0, stream>>>(qkvb, mask, xm);
        gemm128_kernel<2><<<dim3(4, 128), 256, 0, stream>>>(xm, woT, bo + l*768, nullptr,
                                                            h, modsL + 2*768, 768, 768, 4608);
        ln_mod_kernel<<<4096, 256, 0, stream>>>(h, modsL + 3*768, modsL + 4*768, 4608, xm);
        gemm256v2_kernel<1><<<768, 512, 0, stream>>>(xm, w1T, b1 + l*3072, y1, 3072, 768);
        gemm128_kernel<2><<<dim3(4, 128), 256, 0, stream>>>(y1, w2T, b2 + l*768, nullptr,
                                                            h, modsL + 5*768, 768, 3072, 4608);
    }
    ln_mod_kernel<<<4096, 256, 0, stream>>>(h, modsF + 0, modsF + 768, 1536, xm);
    outdot_kernel<<<4096, 256, 0, stream>>>(xm, W_out, out);
}

// Round 6
// 4671.226 us; speedup vs baseline: 1.1045x; 1.0354x over previous
//
#include <hip/hip_runtime.h>
#include <hip/hip_bf16.h>

#define B_   32
#define N_   512
#define D_   768
#define H_   12
#define HID_ 3072
#define L_   12
#define M_   (B_*N_)   // 16384

typedef __attribute__((ext_vector_type(8))) short short8_t;
typedef __attribute__((ext_vector_type(4))) short short4_t;
typedef __attribute__((ext_vector_type(4))) float f32x4;
typedef __hip_bfloat16 bf16;

__device__ __forceinline__ void gll16(const void* g, void* l){
    __builtin_amdgcn_global_load_lds((const __attribute__((address_space(1))) void*)g,
                                     (__attribute__((address_space(3))) void*)l, 16, 0, 0);
}

// ---------------- positional table: ptab[n][d], 512x768 ----------------
__global__ __launch_bounds__(256) void pos_kernel(float* __restrict__ ptab)
{
    int idx = blockIdx.x*256 + threadIdx.x;   // < 512*768
    int d = idx % 768, n = idx / 768;
    int K = (d < 384) ? d : d - 384;
    float ang = (float)n * 3.14159265358979323846f * expf(-(2.0f*(float)K/768.0f) * 7.624618986159398f);
    ptab[idx] = (d < 384) ? sinf(ang) : cosf(ang);
}

// ---------------- embedding: h = x@W_xemb + b + ptab ----------------
__global__ __launch_bounds__(256) void embed_kernel(
    const float* __restrict__ x, const float* __restrict__ Wx,
    const float* __restrict__ bx, const float* __restrict__ ptab,
    float* __restrict__ h)
{
    long idx = (long)blockIdx.x * 256 + threadIdx.x;   // < 16384*768
    int d = (int)(idx % 768);
    long m = idx / 768;
    int n = (int)(m % 512);
    float acc = bx[d] + ptab[n*768 + d];
    const float* xr = x + m * 16;
    #pragma unroll
    for (int k = 0; k < 16; ++k) acc = fmaf(xr[k], Wx[k*768 + d], acc);
    h[idx] = acc;
}

// ---------------- c_silu = silu(ds_table[dataset] + sg_table[spacegroup]) ----------------
__global__ __launch_bounds__(256) void csilu_kernel(
    const float* __restrict__ ds_t, const float* __restrict__ sg_t,
    const int* __restrict__ dataset, const int* __restrict__ sg, float* __restrict__ out)
{
    int idx = blockIdx.x*256 + threadIdx.x;   // 32*768
    int b = idx / 768, d = idx % 768;
    float c = ds_t[dataset[b]*768 + d] + sg_t[sg[b]*768 + d];
    out[idx] = c / (1.0f + expf(-c));
}

// ---------------- mods partials v2: 16-b groups, csilu in LDS ----------------
__global__ __launch_bounds__(256) void mods_part_kernel(
    const float* __restrict__ csilu, const float* __restrict__ W,
    float* __restrict__ part, int Nd2, long wLayerStride)
{
    __shared__ float cs[16][96];
    int n2 = blockIdx.x*256 + threadIdx.x;
    int l = blockIdx.y, z = blockIdx.z;
    int kz = z >> 1, bg = z & 1;
    int L = gridDim.y;
    for (int t = threadIdx.x; t < 16*96; t += 256){
        int bb = t / 96, kk = t - bb*96;
        cs[bb][kk] = csilu[(bg*16 + bb)*768 + kz*96 + kk];
    }
    __syncthreads();
    const float2* Wl = (const float2*)(W + (long)l*wLayerStride);
    float2 acc[16];
    #pragma unroll
    for (int b=0;b<16;b++) acc[b] = make_float2(0.f, 0.f);
    for (int k=0;k<96;++k){
        float2 wv = Wl[(long)(kz*96 + k)*Nd2 + n2];
        #pragma unroll
        for (int b=0;b<16;b++){
            float c = cs[b][k];
            acc[b].x = fmaf(c, wv.x, acc[b].x);
            acc[b].y = fmaf(c, wv.y, acc[b].y);
        }
    }
    float2* pp = (float2*)part + ((long)(kz*L + l)*32 + bg*16)*Nd2 + n2;
    #pragma unroll
    for (int b=0;b<16;b++) pp[(long)b*Nd2] = acc[b];
}

__global__ __launch_bounds__(256) void mods_reduce_kernel(
    const float* __restrict__ part, const float* __restrict__ bias,
    float* __restrict__ out, int Nd, int L)
{
    long idx = (long)blockIdx.x*256 + threadIdx.x;  // over L*32*Nd
    int n = (int)(idx % Nd);
    long r = idx / Nd;
    int b = (int)(r & 31);
    int l = (int)(r >> 5);
    float s = bias[(long)l*Nd + n];
    #pragma unroll
    for (int z=0;z<8;z++) s += part[((long)(z*L + l)*32 + b)*Nd + n];
    out[idx] = s;
}

// ---------------- fused per-layer weight transpose fp32 [K][N] -> bf16 [N][K] ----------------
__global__ __launch_bounds__(256) void transpose4_kernel(
    const float* __restrict__ Wqkv, const float* __restrict__ Wo,
    const float* __restrict__ W1,  const float* __restrict__ W2,
    bf16* __restrict__ wqT, bf16* __restrict__ woT,
    bf16* __restrict__ w1T, bf16* __restrict__ w2T)
{
    __shared__ float t[32][33];
    int tt = blockIdx.x;
    const float* src; bf16* dst; int K, Nd, nx;
    if (tt < 1728){ src=Wqkv; dst=wqT; K=768; Nd=2304; nx=72; }
    else if (tt < 2304){ src=Wo; dst=woT; K=768; Nd=768; nx=24; tt -= 1728; }
    else if (tt < 4608){ src=W1; dst=w1T; K=768; Nd=3072; nx=96; tt -= 2304; }
    else { src=W2; dst=w2T; K=3072; Nd=768; nx=24; tt -= 4608; }
    int n0 = (tt % nx)*32, k0 = (tt / nx)*32;
    int tx = threadIdx.x & 31, ty = threadIdx.x >> 5;   // 32 x 8
    #pragma unroll
    for (int j=0;j<4;j++)
        t[ty + j*8][tx] = src[(long)(k0 + ty + j*8)*Nd + n0 + tx];
    __syncthreads();
    #pragma unroll
    for (int j=0;j<4;j++)
        dst[(long)(n0 + ty + j*8)*K + k0 + tx] = __float2bfloat16(t[tx][ty + j*8]);
}

// ---------------- LayerNorm + modulate -> bf16 (wave-per-row, float4) ----------------
__global__ __launch_bounds__(256) void ln_mod_kernel(
    const float* __restrict__ h, const float* __restrict__ shiftB,
    const float* __restrict__ scaleB, int modsStride, bf16* __restrict__ out)
{
    int wave = threadIdx.x >> 6, lane = threadIdx.x & 63;
    long row = (long)blockIdx.x*4 + wave;
    int b = (int)(row >> 9);
    const float4* xr = (const float4*)(h + row*768);
    float4 v[3];
    float s = 0.f, ss = 0.f;
    #pragma unroll
    for (int i=0;i<3;i++){
        v[i] = xr[lane + i*64];
        s  += v[i].x + v[i].y + v[i].z + v[i].w;
        ss += v[i].x*v[i].x + v[i].y*v[i].y + v[i].z*v[i].z + v[i].w*v[i].w;
    }
    #pragma unroll
    for (int o=1;o<64;o<<=1){ s += __shfl_xor(s,o,64); ss += __shfl_xor(ss,o,64); }
    float mean = s * (1.0f/768.0f);
    float var  = ss * (1.0f/768.0f) - mean*mean;
    float rstd = rsqrtf(var + 1e-6f);
    const float4* sh4 = (const float4*)(shiftB + (long)b*modsStride);
    const float4* sc4 = (const float4*)(scaleB + (long)b*modsStride);
    short4_t* orow = (short4_t*)(out + row*768);
    #pragma unroll
    for (int i=0;i<3;i++){
        float4 sh = sh4[lane + i*64];
        float4 sc = sc4[lane + i*64];
        float o0 = (v[i].x-mean)*rstd*(1.f+sc.x) + sh.x;
        float o1 = (v[i].y-mean)*rstd*(1.f+sc.y) + sh.y;
        float o2 = (v[i].z-mean)*rstd*(1.f+sc.z) + sh.z;
        float o3 = (v[i].w-mean)*rstd*(1.f+sc.w) + sh.w;
        bf16 b0 = __float2bfloat16(o0), b1 = __float2bfloat16(o1);
        bf16 b2 = __float2bfloat16(o2), b3 = __float2bfloat16(o3);
        short4_t pk;
        pk[0] = *(short*)&b0; pk[1] = *(short*)&b1;
        pk[2] = *(short*)&b2; pk[3] = *(short*)&b3;
        orow[lane + i*64] = pk;
    }
}

// gelu(tanh approx) via sigmoid identity: 0.5x(1+tanh(z)) = x * sigmoid(2z)
__device__ __forceinline__ float gelu_f(float x){
    float z2 = 1.5957691216057308f * x * (1.0f + 0.044715f*x*x);
    return x / (1.0f + __expf(-z2));
}

// ---------------- 128x192 pipelined bf16 MFMA GEMM (round-3, 4680-verified, FROZEN) ----------------
template<int MODE>
__global__ __launch_bounds__(256, 2) void gemm128_kernel(
    const bf16* __restrict__ A, const bf16* __restrict__ Bw,
    const float* __restrict__ bias, bf16* __restrict__ outBf,
    float* __restrict__ hres, const float* __restrict__ gate,
    int Nd, int Kd, int gateStride)
{
    __shared__ __align__(16) short lds[40960];   // 80 KiB
    int tid = threadIdx.x;
    int lane = tid & 63, wave = tid >> 6;
    int frow = lane & 15, g = lane >> 4;

    int nx = gridDim.x;
    int bid = blockIdx.y * nx + blockIdx.x;
    int xcd = bid & 7;
    int wq  = bid >> 3;
    int mt  = xcd * 16 + (wq & 15);
    int ct  = wq >> 4;
    int m0 = mt * 128, n0 = ct * 192;
    int wn = wave * 48;

    const short* Ag = (const short*)A;
    const short* Bg = (const short*)Bw;
    int r0 = tid >> 3, s0 = (tid & 7) ^ ((tid >> 3) & 7);
    const short* aSrc = Ag + (long)(m0 + r0)*Kd + s0*8;
    const short* bSrc = Bg + (long)(n0 + r0)*Kd + s0*8;
    long rj = (long)32*Kd;
    int wbase = wave*512;

    int aFrag = frow*64;
    int bFrag = (wn + frow)*64;
    int slotK0 = (g ^ (frow & 7))*8;
    int slotK1 = ((4+g) ^ (frow & 7))*8;

    f32x4 acc[8][3];
    #pragma unroll
    for (int i=0;i<8;i++)
        #pragma unroll
        for (int j=0;j<3;j++) acc[i][j] = (f32x4){0.f,0.f,0.f,0.f};

    int NT = Kd >> 6;

#define STAGE(kt, ps) { \
    int par_ = (kt)&1; \
    if ((ps)==0){ \
        short* d_ = &lds[par_*8192 + wbase]; \
        gll16(aSrc +        (long)(kt)*64, d_); \
        gll16(aSrc +   rj + (long)(kt)*64, d_ + 2048); \
        gll16(aSrc + 2*rj + (long)(kt)*64, d_ + 4096); \
        gll16(aSrc + 3*rj + (long)(kt)*64, d_ + 6144); \
    } else { \
        short* d_ = &lds[16384 + par_*12288 + wbase]; \
        gll16(bSrc +        (long)(kt)*64, d_); \
        gll16(bSrc +   rj + (long)(kt)*64, d_ + 2048); \
        gll16(bSrc + 2*rj + (long)(kt)*64, d_ + 4096); \
        gll16(bSrc + 3*rj + (long)(kt)*64, d_ + 6144); \
        gll16(bSrc + 4*rj + (long)(kt)*64, d_ + 8192); \
        gll16(bSrc + 5*rj + (long)(kt)*64, d_ + 10240); \
    } }

    STAGE(0,0); STAGE(0,1);

    for (int kt=0; kt<NT; ++kt){
        int pA  = (kt&1)*8192;
        int pBb = 16384 + (kt&1)*12288;
        bool pf = (kt+1 < NT);
        if (pf){
            STAGE(kt+1, 0);
            asm volatile("s_waitcnt vmcnt(4)" ::: "memory");
        } else {
            asm volatile("s_waitcnt vmcnt(0)" ::: "memory");
        }
        __builtin_amdgcn_s_barrier();
        __builtin_amdgcn_sched_barrier(0);
        if (pf) STAGE(kt+1, 1);
        short8_t af0[8], af1[8], bf0[3], bf1[3];
        #pragma unroll
        for (int i=0;i<8;i++){
            af0[i] = *(const short8_t*)&lds[pA + aFrag + i*1024 + slotK0];
            af1[i] = *(const short8_t*)&lds[pA + aFrag + i*1024 + slotK1];
        }
        #pragma unroll
        for (int j=0;j<3;j++){
            bf0[j] = *(const short8_t*)&lds[pBb + bFrag + j*1024 + slotK0];
            bf1[j] = *(const short8_t*)&lds[pBb + bFrag + j*1024 + slotK1];
        }
        __builtin_amdgcn_s_setprio(1);
        #pragma unroll
        for (int i=0;i<8;i++)
            #pragma unroll
            for (int j=0;j<3;j++)
                acc[i][j] = __builtin_amdgcn_mfma_f32_16x16x32_bf16(af0[i], bf0[j], acc[i][j], 0, 0, 0);
        #pragma unroll
        for (int i=0;i<8;i++)
            #pragma unroll
            for (int j=0;j<3;j++)
                acc[i][j] = __builtin_amdgcn_mfma_f32_16x16x32_bf16(af1[i], bf1[j], acc[i][j], 0, 0, 0);
        __builtin_amdgcn_s_setprio(0);
        __builtin_amdgcn_sched_barrier(0);
        __builtin_amdgcn_s_barrier();
        __builtin_amdgcn_sched_barrier(0);
    }
#undef STAGE

    int rbase = m0 + g*4;
    int cbase = n0 + wn + frow;
    float bv0 = bias[cbase], bv1 = bias[cbase+16], bv2 = bias[cbase+32];
    #pragma unroll
    for (int i=0;i<8;i++){
        #pragma unroll
        for (int r=0;r<4;r++){
            int row = rbase + i*16 + r;
            float v0 = acc[i][0][r] + bv0;
            float v1 = acc[i][1][r] + bv1;
            float v2 = acc[i][2][r] + bv2;
            if (MODE == 0){
                bf16* o_ = outBf + (long)row*Nd + cbase;
                o_[0]  = __float2bfloat16(v0);
                o_[16] = __float2bfloat16(v1);
                o_[32] = __float2bfloat16(v2);
            } else if (MODE == 1){
                bf16* o_ = outBf + (long)row*Nd + cbase;
                o_[0]  = __float2bfloat16(gelu_f(v0));
                o_[16] = __float2bfloat16(gelu_f(v1));
                o_[32] = __float2bfloat16(gelu_f(v2));
            } else {
                int bb = row >> 9;
                const float* gp = gate + (long)bb*gateStride + cbase;
                float* hp = hres + (long)row*768 + cbase;
                hp[0]  += gp[0]  * v0;
                hp[16] += gp[16] * v1;
                hp[32] += gp[32] * v2;
            }
        }
    }
}

// ---------------- MFMA flash attention, double-buffered K/V (T14 async-stage) ----------------
// Per kt: issue next tile's 4 global loads to regs BEFORE compute (fly under
// ~2000cyc of QK/softmax/PV), after compute vmcnt(0) (already landed) +
// reg->LDS write into the other buffer; ONE barrier per iteration (was 2).
// LDS 48KB -> 3 blocks/CU.
__global__ __launch_bounds__(256) void attn_mfma_kernel(
    const bf16* __restrict__ qkv, const int* __restrict__ mask, bf16* __restrict__ o)
{
    __shared__ __align__(16) short Ks[2][64][72];
    __shared__ __align__(16) short Vt[2][64][72];
    __shared__ __align__(16) short Ps[4][16][72];
    __shared__ float maskf[512];
    int tid = threadIdx.x, lane = tid & 63, wave = tid >> 6;
    int qt = blockIdx.x, hh = blockIdx.y, b = blockIdx.z;
    long base = (long)b * 512 * 2304;
    const short* qkvs = (const short*)qkv;

    maskf[tid]       = mask[b*512 + tid]       ? -1e30f : 0.0f;
    maskf[tid + 256] = mask[b*512 + tid + 256] ? -1e30f : 0.0f;

    int c = lane & 15, g = lane >> 4;
    int qrowA = qt*64 + wave*16 + c;
    const short* qptr = qkvs + base + (long)qrowA*2304 + hh*64 + g*8;
    short8_t qa0 = *(const short8_t*)qptr;
    short8_t qa1 = *(const short8_t*)(qptr + 32);

    f32x4 oacc[4];
    #pragma unroll
    for (int j=0;j<4;j++) oacc[j] = (f32x4){0.f,0.f,0.f,0.f};
    float m_r[4], l_r[4];
    #pragma unroll
    for (int r=0;r<4;r++){ m_r[r] = -50.0f; l_r[r] = 0.0f; }

    int kp = (tid & 31)*2, gv = tid >> 5;
    const short* kgbase = qkvs + base + 768  + hh*64;
    const short* vgbase = qkvs + base + 1536 + hh*64 + gv*8;

    int r0s = tid >> 3, c0s = (tid & 7)*8;      // K row/col for this thread
    int r1s = r0s + 32;

    short8_t ka, kb2, va, vb;
#define LDREGS(kt) { \
    ka  = *(const short8_t*)(kgbase + (long)((kt)*64 + r0s)*2304 + c0s); \
    kb2 = *(const short8_t*)(kgbase + (long)((kt)*64 + r1s)*2304 + c0s); \
    va  = *(const short8_t*)(vgbase + (long)((kt)*64 + kp    )*2304); \
    vb  = *(const short8_t*)(vgbase + (long)((kt)*64 + kp + 1)*2304); }
#define WRLDS(bf_) { \
    *(short8_t*)&Ks[bf_][r0s][c0s] = ka; \
    *(short8_t*)&Ks[bf_][r1s][c0s] = kb2; \
    _Pragma("unroll") \
    for (int e=0;e<8;e++){ \
        unsigned int pack = (unsigned int)(unsigned short)va[e] \
                          | ((unsigned int)(unsigned short)vb[e] << 16); \
        *(unsigned int*)&Vt[bf_][gv*8 + e][kp] = pack; } }

    LDREGS(0);
    WRLDS(0);
    __syncthreads();

    for (int kt=0; kt<8; ++kt){
        int cb = kt & 1;
        if (kt < 7) LDREGS(kt+1);
        f32x4 s[4];
        #pragma unroll
        for (int j=0;j<4;j++){
            short8_t kb0 = *(const short8_t*)&Ks[cb][j*16 + c][g*8];
            short8_t kb1 = *(const short8_t*)&Ks[cb][j*16 + c][g*8 + 32];
            f32x4 z = (f32x4){0.f,0.f,0.f,0.f};
            z = __builtin_amdgcn_mfma_f32_16x16x32_bf16(qa0, kb0, z, 0, 0, 0);
            z = __builtin_amdgcn_mfma_f32_16x16x32_bf16(qa1, kb1, z, 0, 0, 0);
            s[j] = z;
        }
        #pragma unroll
        for (int j=0;j<4;j++){
            float mbj = maskf[kt*64 + j*16 + c];
            #pragma unroll
            for (int r=0;r<4;r++) s[j][r] = s[j][r]*0.125f + mbj;
        }
        #pragma unroll
        for (int r=0;r<4;r++){
            float tm = fmaxf(fmaxf(s[0][r], s[1][r]), fmaxf(s[2][r], s[3][r]));
            #pragma unroll
            for (int o_=1;o_<16;o_<<=1) tm = fmaxf(tm, __shfl_xor(tm, o_, 64));
            float mn  = fmaxf(m_r[r], tm);
            float fac = __expf(m_r[r] - mn);
            m_r[r] = mn;
            float ls = l_r[r]*fac;
            #pragma unroll
            for (int j=0;j<4;j++){
                float p = __expf(s[j][r] - mn);
                s[j][r] = p;
                ls += p;
            }
            l_r[r] = ls;
            #pragma unroll
            for (int j=0;j<4;j++) oacc[j][r] *= fac;
        }
        #pragma unroll
        for (int j=0;j<4;j++)
            #pragma unroll
            for (int r=0;r<4;r++)
                *(bf16*)&Ps[wave][g*4 + r][j*16 + c] = __float2bfloat16(s[j][r]);
        short8_t pa0 = *(const short8_t*)&Ps[wave][c][g*8];
        short8_t pa1 = *(const short8_t*)&Ps[wave][c][g*8 + 32];
        #pragma unroll
        for (int j=0;j<4;j++){
            short8_t vb0 = *(const short8_t*)&Vt[cb][j*16 + c][g*8];
            short8_t vb1 = *(const short8_t*)&Vt[cb][j*16 + c][g*8 + 32];
            oacc[j] = __builtin_amdgcn_mfma_f32_16x16x32_bf16(pa0, vb0, oacc[j], 0, 0, 0);
            oacc[j] = __builtin_amdgcn_mfma_f32_16x16x32_bf16(pa1, vb1, oacc[j], 0, 0, 0);
        }
        if (kt < 7){
            asm volatile("s_waitcnt vmcnt(0)" ::: "memory");
            WRLDS(cb ^ 1);
        }
        __syncthreads();
    }
#undef LDREGS
#undef WRLDS

    #pragma unroll
    for (int r=0;r<4;r++){
        float lt = l_r[r];
        #pragma unroll
        for (int o_=1;o_<16;o_<<=1) lt += __shfl_xor(lt, o_, 64);
        l_r[r] = 1.0f / lt;
    }
    int qrowC = qt*64 + wave*16 + g*4;
    bf16* orow = o + ((long)b*512 + qrowC)*768 + hh*64;
    #pragma unroll
    for (int r=0;r<4;r++)
        #pragma unroll
        for (int j=0;j<4;j++)
            orow[(long)r*768 + j*16 + c] = __float2bfloat16(oacc[j][r] * l_r[r]);
}

// ---------------- final: out = xm @ W_out ----------------
__global__ __launch_bounds__(256) void outdot_kernel(
    const bf16* __restrict__ xm, const float* __restrict__ Wout, float* __restrict__ out)
{
    int tid=threadIdx.x, lane=tid&63, wave=tid>>6;
    long row = (long)blockIdx.x*4 + wave;
    const bf16* xr = xm + row*768;
    float acc = 0.f;
    #pragma unroll
    for (int i=0;i<12;i++){ int d = lane + i*64; acc = fmaf(__bfloat162float(xr[d]), Wout[d], acc); }
    #pragma unroll
    for (int o_=1;o_<64;o_<<=1) acc += __shfl_xor(acc, o_, 64);
    if (lane==0) out[row] = acc;
}

extern "C" void kernel_launch(void* const* d_in, const int* in_sizes, int n_in,
                              void* d_out, int out_size, void* d_ws, size_t ws_size,
                              hipStream_t stream)
{
    const float* x      = (const float*)d_in[0];
    const float* W_xemb = (const float*)d_in[1];
    const float* b_xemb = (const float*)d_in[2];
    const float* ds_t   = (const float*)d_in[3];
    const float* sg_t   = (const float*)d_in[4];
    const float* Wqkv   = (const float*)d_in[5];
    const float* bqkv   = (const float*)d_in[6];
    const float* Wo     = (const float*)d_in[7];
    const float* bo     = (const float*)d_in[8];
    const float* W1     = (const float*)d_in[9];
    const float* b1     = (const float*)d_in[10];
    const float* W2     = (const float*)d_in[11];
    const float* b2     = (const float*)d_in[12];
    const float* Wada   = (const float*)d_in[13];
    const float* bada   = (const float*)d_in[14];
    const float* Wada_f = (const float*)d_in[15];
    const float* bada_f = (const float*)d_in[16];
    const float* W_out  = (const float*)d_in[17];
    const int* dataset  = (const int*)d_in[18];
    const int* sgroup   = (const int*)d_in[19];
    const int* mask     = (const int*)d_in[20];
    float* out = (float*)d_out;

    char* ws = (char*)d_ws;
    size_t off = 0;
    auto alloc = [&](size_t bytes)->void*{
        void* p = ws + off; off += (bytes + 255) & ~(size_t)255; return p; };
    float* h     = (float*)alloc((size_t)M_*768*4);         // 50.3 MB
    float* csilu = (float*)alloc((size_t)32*768*4);
    float* modsA = (float*)alloc((size_t)12*32*4608*4);     // 7.1 MB
    float* modsF = (float*)alloc((size_t)32*1536*4);
    float* ptab  = (float*)alloc((size_t)512*768*4);        // 1.6 MB
    bf16*  xm    = (bf16*) alloc((size_t)M_*768*2);         // 25.2 MB
    bf16*  wbuf  = (bf16*) alloc((size_t)7077888*2);        // 14.2 MB per-layer bf16 weights
    bf16*  big   = (bf16*) alloc((size_t)M_*3072*2);        // 100.7 MB (qkv / y1 / mods partials)
    bf16* qkvb = big;
    bf16* y1   = big;
    float* partA = (float*)big;                      // 56.6 MB (pre-loop only)
    float* partF = partA + (size_t)8*12*32*4608;
    bf16* wqT = wbuf;                 // [2304][768]
    bf16* woT = wqT + 2304*768;       // [768][768]
    bf16* w1T = woT + 768*768;        // [3072][768]
    bf16* w2T = w1T + 3072*768;       // [768][3072]

    pos_kernel<<<1536, 256, 0, stream>>>(ptab);
    embed_kernel<<<49152, 256, 0, stream>>>(x, W_xemb, b_xemb, ptab, h);
    csilu_kernel<<<96, 256, 0, stream>>>(ds_t, sg_t, dataset, sgroup, csilu);
    mods_part_kernel<<<dim3(9,12,16), 256, 0, stream>>>(csilu, Wada, partA, 2304, (long)768*4608);
    mods_reduce_kernel<<<6912, 256, 0, stream>>>(partA, bada, modsA, 4608, 12);
    mods_part_kernel<<<dim3(3,1,16), 256, 0, stream>>>(csilu, Wada_f, partF, 768, 0);
    mods_reduce_kernel<<<192, 256, 0, stream>>>(partF, bada_f, modsF, 1536, 1);

    for (int l=0; l<12; ++l){
        const float* modsL = modsA + (long)l*32*4608;
        transpose4_kernel<<<6912, 256, 0, stream>>>(
            Wqkv + (long)l*768*2304, Wo + (long)l*768*768,
            W1 + (long)l*768*3072,  W2 + (long)l*3072*768,
            wqT, woT, w1T, w2T);

        ln_mod_kernel<<<4096, 256, 0, stream>>>(h, modsL + 0*768, modsL + 1*768, 4608, xm);
        gemm128_kernel<0><<<dim3(12, 128), 256, 0, stream>>>(xm, wqT, bqkv + l*2304, qkvb,
                                                             nullptr, nullptr, 2304, 768, 0);
        attn_mfma_kernel<<<dim3(8, 12, 32), 256, 0, stream>>>(qkvb, mask, xm);
        gemm128_kernel<2><<<dim3(4, 128), 256, 0, stream>>>(xm, woT, bo + l*768, nullptr,
                                                            h, modsL + 2*768, 768, 768, 4608);
        ln_mod_kernel<<<4096, 256, 0, stream>>>(h, modsL + 3*768, modsL + 4*768, 4608, xm);
        gemm128_kernel<1><<<dim3(16, 128), 256, 0, stream>>>(xm, w1T, b1 + l*3072, y1,
                                                             nullptr, nullptr, 3072, 768, 0);
        gemm128_kernel<2><<<dim3(4, 128), 256, 0, stream>>>(y1, w2T, b2 + l*768, nullptr,
                                                            h, modsL + 5*768, 768, 3072, 4608);
    }
    ln_mod_kernel<<<4096, 256, 0, stream>>>(h, modsF + 0, modsF + 768, 1536, xm);
    outdot_kernel<<<4096, 256, 0, stream>>>(xm, W_out, out);
}